// Round 5
// baseline (492.480 us; speedup 1.0000x reference)
//
#include <hip/hip_runtime.h>
#include <hip/hip_bf16.h>

// PointSelfAttention R5:
//   k_prep_w : w_qkv/w_out -> bf16 [col][K]
//   k_prep_tbl : per-head RBF bias table (1024 entries)
//   k_qkv  : GEMM -> q/k panels [key][d], V panels TRANSPOSED [d][key]; B direct from L2,
//            A via LDS double-buffer + reg prefetch, 1 barrier per BK=32
//   k_fused: per molecule (8 waves = 8 heads): S=qk^T(+bias), softmax, PV, out-proj,
//            residual+LN. Operand frags direct from global; P/agg in XOR-swizzled LDS.

#define HID 512
#define TBL 1024
#define DMAX 12.0f

typedef __attribute__((ext_vector_type(4))) float f32x4;
typedef __attribute__((ext_vector_type(8))) short bhalf8;

__device__ __forceinline__ short f2bf(float f) {
    union { float f; unsigned u; } x; x.f = f;
    unsigned u = x.u;
    unsigned r = (u + 0x7FFFu + ((u >> 16) & 1u)) >> 16;  // RNE
    return (short)r;
}

// ---- prep: transpose weights to bf16 [cols][K] ----
__global__ __launch_bounds__(256) void k_prep_w(const float* __restrict__ w_qkv,
                                                const float* __restrict__ w_out,
                                                short* __restrict__ wqT,
                                                short* __restrict__ woT) {
    __shared__ short tile[64][68];
    const int t = threadIdx.x;
    int bt = blockIdx.x;
    const float* src; short* dst; int sld, tk, tc;
    if (bt < 192) { src = w_qkv; dst = wqT; sld = 1536; tk = bt & 7; tc = bt >> 3; }
    else { int b2 = bt - 192; src = w_out; dst = woT; sld = 512; tk = b2 & 7; tc = b2 >> 3; }
#pragma unroll
    for (int p = 0; p < 4; ++p) {
        int s = t + 256 * p;
        int r = s >> 4, sg = s & 15;
        const float4 v = *(const float4*)(src + (tk * 64 + r) * sld + tc * 64 + sg * 4);
        tile[r][sg * 4 + 0] = f2bf(v.x);
        tile[r][sg * 4 + 1] = f2bf(v.y);
        tile[r][sg * 4 + 2] = f2bf(v.z);
        tile[r][sg * 4 + 3] = f2bf(v.w);
    }
    __syncthreads();
#pragma unroll
    for (int p = 0; p < 16; ++p) {
        int o = t + 256 * p;
        int c = o >> 6, k = o & 63;
        dst[(tc * 64 + c) * 512 + tk * 64 + k] = tile[k][c];
    }
}

// ---- prep: per-head bias(d) table [8][1024] ----
__global__ __launch_bounds__(256) void k_prep_tbl(const float* __restrict__ centers,
                                                  const float* __restrict__ w_rbf,
                                                  const float* __restrict__ b_rbf,
                                                  float* __restrict__ tbl) {
    int idx = blockIdx.x * 256 + threadIdx.x;   // 8 heads * 1024
    int hh = idx >> 10, i = idx & (TBL - 1);
    float d = (float)i * (DMAX / (float)(TBL - 1));
    float s = b_rbf[hh];
    const float invw = 1.0f / 0.0625f;          // width = (8/32)^2
#pragma unroll 4
    for (int r = 0; r < 32; ++r) {
        float tt = d - centers[r];
        s += w_rbf[r * 8 + hh] * expf(-(tt * tt) * invw);
    }
    tbl[idx] = s;
}

// ---- QKV GEMM: M=128 x N=256 per block; B-frags direct from L2; A dbuf LDS ----
__global__ __launch_bounds__(512) void k_qkv(const float* __restrict__ h,
                                             const float* __restrict__ b_qkv,
                                             const short* __restrict__ wqT,
                                             short* __restrict__ qkvb,
                                             int molbase) {
    __shared__ __align__(16) short As[2][128 * 40];    // 20 KB
    const int t = threadIdx.x;
    const int lane = t & 63, wave = t >> 6;
    const int l16 = lane & 15, g = lane >> 4;
    const int wrow = wave >> 2, wcol = wave & 3;       // 2 x 4 wave grid
    const int R0 = molbase * 64 + blockIdx.x * 128;
    const int C0 = blockIdx.y * 256;

    f32x4 acc[4][4];
#pragma unroll
    for (int i = 0; i < 4; ++i)
#pragma unroll
        for (int j = 0; j < 4; ++j) acc[i][j] = (f32x4){0.f, 0.f, 0.f, 0.f};

    const int arow = t >> 2, aseg = t & 3;
    const float* hsrc = h + (size_t)(R0 + arow) * HID + aseg * 8;

    int brow[4];
#pragma unroll
    for (int nt = 0; nt < 4; ++nt)
        brow[nt] = (C0 + wcol * 64 + nt * 16 + l16) * HID + g * 8;

    // prologue: chunk0 -> LDS[0]; chunk1 -> regs; B(0) -> regs
    {
        float4 a0 = *(const float4*)(hsrc);
        float4 a1 = *(const float4*)(hsrc + 4);
        short s8[8];
        s8[0] = f2bf(a0.x); s8[1] = f2bf(a0.y); s8[2] = f2bf(a0.z); s8[3] = f2bf(a0.w);
        s8[4] = f2bf(a1.x); s8[5] = f2bf(a1.y); s8[6] = f2bf(a1.z); s8[7] = f2bf(a1.w);
        *(int4*)(&As[0][arow * 40 + aseg * 8]) = *(int4*)s8;
    }
    float4 p0 = *(const float4*)(hsrc + 32);
    float4 p1 = *(const float4*)(hsrc + 36);
    int4 bw[4];
#pragma unroll
    for (int nt = 0; nt < 4; ++nt) bw[nt] = *(const int4*)(wqT + brow[nt]);
    __syncthreads();

    for (int kc = 0; kc < 16; ++kc) {
        int4 bn[4];
        if (kc < 15) {
#pragma unroll
            for (int nt = 0; nt < 4; ++nt)
                bn[nt] = *(const int4*)(wqT + brow[nt] + (kc + 1) * 32);
        }
        float4 n0, n1;
        if (kc < 14) {
            n0 = *(const float4*)(hsrc + (kc + 2) * 32);
            n1 = *(const float4*)(hsrc + (kc + 2) * 32 + 4);
        }
        bhalf8 af[4];
#pragma unroll
        for (int mt = 0; mt < 4; ++mt)
            af[mt] = *(const bhalf8*)(&As[kc & 1][(wrow * 64 + mt * 16 + l16) * 40 + g * 8]);
#pragma unroll
        for (int mt = 0; mt < 4; ++mt)
#pragma unroll
            for (int nt = 0; nt < 4; ++nt)
                acc[mt][nt] = __builtin_amdgcn_mfma_f32_16x16x32_bf16(
                    af[mt], *(bhalf8*)&bw[nt], acc[mt][nt], 0, 0, 0);
        if (kc < 15) {
            short s8[8];
            s8[0] = f2bf(p0.x); s8[1] = f2bf(p0.y); s8[2] = f2bf(p0.z); s8[3] = f2bf(p0.w);
            s8[4] = f2bf(p1.x); s8[5] = f2bf(p1.y); s8[6] = f2bf(p1.z); s8[7] = f2bf(p1.w);
            *(int4*)(&As[(kc + 1) & 1][arow * 40 + aseg * 8]) = *(int4*)s8;
            __syncthreads();
        }
        p0 = n0; p1 = n1;
#pragma unroll
        for (int nt = 0; nt < 4; ++nt) bw[nt] = bn[nt];
    }

    // epilogue: +bias; q scaled; V written transposed [d][key]
    const int sec = C0 >> 9;
    const float mul = (sec == 0) ? 0.125f : 1.0f;
#pragma unroll
    for (int nt = 0; nt < 4; ++nt) {
        int c = C0 + wcol * 64 + nt * 16 + l16;
        float bv = b_qkv[c];
        int head = (c >> 6) & 7, d = c & 63;
#pragma unroll
        for (int mt = 0; mt < 4; ++mt) {
            int rowg = R0 + wrow * 64 + mt * 16 + g * 4;
            int mol_local = (rowg >> 6) - molbase;
            int rloc = rowg & 63;
            short* panel = qkvb + (size_t)((mol_local * 3 + sec) * 8 + head) * 4096;
            if (sec == 2) {
#pragma unroll
                for (int r = 0; r < 4; ++r)
                    panel[d * 64 + rloc + r] = f2bf(acc[mt][nt][r] + bv);
            } else {
#pragma unroll
                for (int r = 0; r < 4; ++r)
                    panel[(rloc + r) * 64 + d] = f2bf((acc[mt][nt][r] + bv) * mul);
            }
        }
    }
}

// ---- fused attention + out-proj + residual + LayerNorm; 1 block = 1 molecule ----
__global__ __launch_bounds__(512) void k_fused(const short* __restrict__ qkvb,
                                               const float* __restrict__ pos,
                                               const float* __restrict__ tbl,
                                               const float* __restrict__ h,
                                               const short* __restrict__ woT,
                                               const float* __restrict__ b_out,
                                               const float* __restrict__ gamma,
                                               const float* __restrict__ beta,
                                               float* __restrict__ out,
                                               int molbase) {
    __shared__ __align__(16) short uP[8 * 4096];   // per-wave P[64][64] -> agg[64][512]
    __shared__ float s_tbl[8 * 1032];
    __shared__ float s_px[64], s_py[64], s_pz[64];
    __shared__ float red[64 * 16];
    __shared__ float mr[64 * 2];

    const int t = threadIdx.x;
    const int wave = t >> 6, lane = t & 63;
    const int l16 = lane & 15, g = lane >> 4;
    const int mol_local = blockIdx.x;
    const int rowbase = (molbase + mol_local) * 64;

    for (int i = t; i < 8 * TBL; i += 512)
        s_tbl[(i >> 10) * 1032 + (i & (TBL - 1))] = tbl[i];
    if (t < 64) {
        s_px[t] = pos[(rowbase + t) * 3 + 0];
        s_py[t] = pos[(rowbase + t) * 3 + 1];
        s_pz[t] = pos[(rowbase + t) * 3 + 2];
    }
    __syncthreads();

    const short* qp = qkvb + ((size_t)(mol_local * 3 + 0) * 8 + wave) * 4096;
    const short* kp = qkvb + ((size_t)(mol_local * 3 + 1) * 8 + wave) * 4096;
    const short* vt = qkvb + ((size_t)(mol_local * 3 + 2) * 8 + wave) * 4096;  // [d][key]

    // ---- S = q_scaled . k^T (wave owns full 64x64 of its head) ----
    f32x4 sacc[4][4];
#pragma unroll
    for (int i = 0; i < 4; ++i)
#pragma unroll
        for (int j = 0; j < 4; ++j) sacc[i][j] = (f32x4){0.f, 0.f, 0.f, 0.f};
#pragma unroll
    for (int kk = 0; kk < 2; ++kk) {
        bhalf8 qa[4], kb[4];
#pragma unroll
        for (int mt = 0; mt < 4; ++mt)
            qa[mt] = *(const bhalf8*)(qp + (mt * 16 + l16) * 64 + kk * 32 + g * 8);
#pragma unroll
        for (int nt = 0; nt < 4; ++nt)
            kb[nt] = *(const bhalf8*)(kp + (nt * 16 + l16) * 64 + kk * 32 + g * 8);
#pragma unroll
        for (int mt = 0; mt < 4; ++mt)
#pragma unroll
            for (int nt = 0; nt < 4; ++nt)
                sacc[mt][nt] = __builtin_amdgcn_mfma_f32_16x16x32_bf16(
                    qa[mt], kb[nt], sacc[mt][nt], 0, 0, 0);
    }

    // ---- + RBF bias (LDS table) ----
    const float tscale = (float)(TBL - 1) / DMAX;
    const float* T = s_tbl + wave * 1032;
#pragma unroll
    for (int nt = 0; nt < 4; ++nt) {
        int col = nt * 16 + l16;
        float cx = s_px[col], cy = s_py[col], cz = s_pz[col];
#pragma unroll
        for (int mt = 0; mt < 4; ++mt) {
#pragma unroll
            for (int r = 0; r < 4; ++r) {
                int row = mt * 16 + g * 4 + r;
                float dx = s_px[row] - cx, dy = s_py[row] - cy, dz = s_pz[row] - cz;
                float dd = fmaf(dx, dx, fmaf(dy, dy, dz * dz));
                float dist = sqrtf(fmaxf(dd, 1e-12f));
                float u = fminf(dist, DMAX) * tscale;
                int i = (int)u; if (i > TBL - 2) i = TBL - 2;
                float fr = u - (float)i;
                float t0 = T[i];
                sacc[mt][nt][r] += fmaf(fr, T[i + 1] - t0, t0);
            }
        }
    }

    // ---- softmax rows + P (XOR-swizzled 16-B groups) ----
    float inv[4][4];
    short* Pw = uP + wave * 4096;
#pragma unroll
    for (int mt = 0; mt < 4; ++mt) {
#pragma unroll
        for (int r = 0; r < 4; ++r) {
            float m = fmaxf(fmaxf(sacc[0][mt < 0 ? 0 : 0][r], sacc[0][r < 0 ? 0 : 0][r]), 0.f);
            // (placeholder line removed below — compute properly)
            m = fmaxf(fmaxf(sacc[mt][0][r], sacc[mt][1][r]),
                      fmaxf(sacc[mt][2][r], sacc[mt][3][r]));
#pragma unroll
            for (int off = 1; off < 16; off <<= 1) m = fmaxf(m, __shfl_xor(m, off, 64));
            float e[4], ssum = 0.f;
#pragma unroll
            for (int nt = 0; nt < 4; ++nt) { e[nt] = __expf(sacc[mt][nt][r] - m); ssum += e[nt]; }
#pragma unroll
            for (int off = 1; off < 16; off <<= 1) ssum += __shfl_xor(ssum, off, 64);
            inv[mt][r] = 1.0f / ssum;
            int row = mt * 16 + g * 4 + r;
            int rho = row & 7;
#pragma unroll
            for (int nt = 0; nt < 4; ++nt) {
                int c = nt * 16 + l16;
                Pw[row * 64 + (((c >> 3) ^ rho) << 3) + (c & 7)] = f2bf(e[nt]);
            }
        }
    }

    // ---- PV: agg_head = P @ V  (V^T frags direct from global) ----
    f32x4 oacc[4][4];
#pragma unroll
    for (int i = 0; i < 4; ++i)
#pragma unroll
        for (int j = 0; j < 4; ++j) oacc[i][j] = (f32x4){0.f, 0.f, 0.f, 0.f};
#pragma unroll
    for (int kk = 0; kk < 2; ++kk) {
        bhalf8 pa[4], vb[4];
#pragma unroll
        for (int mt = 0; mt < 4; ++mt)
            pa[mt] = *(const bhalf8*)(Pw + (mt * 16 + l16) * 64 +
                                      (((kk * 4 + g) ^ (l16 & 7)) << 3));
#pragma unroll
        for (int nt = 0; nt < 4; ++nt)
            vb[nt] = *(const bhalf8*)(vt + (nt * 16 + l16) * 64 + kk * 32 + g * 8);
#pragma unroll
        for (int mt = 0; mt < 4; ++mt)
#pragma unroll
            for (int nt = 0; nt < 4; ++nt)
                oacc[mt][nt] = __builtin_amdgcn_mfma_f32_16x16x32_bf16(
                    pa[mt], vb[nt], oacc[mt][nt], 0, 0, 0);
    }
#pragma unroll
    for (int mt = 0; mt < 4; ++mt)
#pragma unroll
        for (int nt = 0; nt < 4; ++nt)
#pragma unroll
            for (int r = 0; r < 4; ++r) oacc[mt][nt][r] *= inv[mt][r];

    __syncthreads();   // all waves done reading P; uP becomes agg[64][512]

#pragma unroll
    for (int mt = 0; mt < 4; ++mt) {
#pragma unroll
        for (int r = 0; r < 4; ++r) {
            int row = mt * 16 + g * 4 + r;
            int rho = row & 7;
#pragma unroll
            for (int nt = 0; nt < 4; ++nt) {
                int c = wave * 64 + nt * 16 + l16;
                uP[row * 512 + (((c >> 3) ^ rho) << 3) + (c & 7)] = f2bf(oacc[mt][nt][r]);
            }
        }
    }
    __syncthreads();

    // ---- out-proj: wave owns cols wave*64..+63; woT frags from L2; no barriers ----
    f32x4 pacc[4][4];
#pragma unroll
    for (int i = 0; i < 4; ++i)
#pragma unroll
        for (int j = 0; j < 4; ++j) pacc[i][j] = (f32x4){0.f, 0.f, 0.f, 0.f};
#pragma unroll 4
    for (int kc = 0; kc < 16; ++kc) {
        bhalf8 af[4], bw[4];
#pragma unroll
        for (int mt = 0; mt < 4; ++mt)
            af[mt] = *(const bhalf8*)(uP + (mt * 16 + l16) * 512 +
                                      (((kc * 4 + g) ^ (l16 & 7)) << 3));
#pragma unroll
        for (int nt = 0; nt < 4; ++nt)
            bw[nt] = *(const bhalf8*)(woT + (size_t)(wave * 64 + nt * 16 + l16) * HID +
                                      kc * 32 + g * 8);
#pragma unroll
        for (int mt = 0; mt < 4; ++mt)
#pragma unroll
            for (int nt = 0; nt < 4; ++nt)
                pacc[mt][nt] = __builtin_amdgcn_mfma_f32_16x16x32_bf16(
                    af[mt], bw[nt], pacc[mt][nt], 0, 0, 0);
    }

    // ---- + b_out + residual; LN partials ----
#pragma unroll
    for (int mt = 0; mt < 4; ++mt) {
#pragma unroll
        for (int r = 0; r < 4; ++r) {
            int row = mt * 16 + g * 4 + r;
            float rs = 0.f, rq = 0.f;
#pragma unroll
            for (int nt = 0; nt < 4; ++nt) {
                int col = wave * 64 + nt * 16 + l16;
                float v = pacc[mt][nt][r] + b_out[col] +
                          h[(size_t)(rowbase + row) * HID + col];
                pacc[mt][nt][r] = v;
                rs += v;
                rq = fmaf(v, v, rq);
            }
#pragma unroll
            for (int off = 1; off < 16; off <<= 1) {
                rs += __shfl_xor(rs, off, 64);
                rq += __shfl_xor(rq, off, 64);
            }
            if (l16 == 0) {
                red[row * 16 + wave * 2 + 0] = rs;
                red[row * 16 + wave * 2 + 1] = rq;
            }
        }
    }
    __syncthreads();
    if (t < 64) {
        float s = 0.f, q = 0.f;
#pragma unroll
        for (int w = 0; w < 8; ++w) {
            s += red[t * 16 + w * 2 + 0];
            q += red[t * 16 + w * 2 + 1];
        }
        float mean = s * (1.0f / 512.0f);
        float var = q * (1.0f / 512.0f) - mean * mean;
        mr[t * 2 + 0] = mean;
        mr[t * 2 + 1] = rsqrtf(var + 1e-5f);
    }
    __syncthreads();
#pragma unroll
    for (int mt = 0; mt < 4; ++mt) {
#pragma unroll
        for (int r = 0; r < 4; ++r) {
            int row = mt * 16 + g * 4 + r;
            float mean = mr[row * 2 + 0], rstd = mr[row * 2 + 1];
#pragma unroll
            for (int nt = 0; nt < 4; ++nt) {
                int col = wave * 64 + nt * 16 + l16;
                out[(size_t)(rowbase + row) * HID + col] =
                    fmaf((pacc[mt][nt][r] - mean) * rstd, gamma[col], beta[col]);
            }
        }
    }
}

extern "C" void kernel_launch(void* const* d_in, const int* in_sizes, int n_in,
                              void* d_out, int out_size, void* d_ws, size_t ws_size,
                              hipStream_t stream) {
    (void)in_sizes; (void)n_in; (void)out_size; (void)ws_size;
    const float* h       = (const float*)d_in[0];
    const float* pos     = (const float*)d_in[1];
    // d_in[2] = batch (unused: equal-size contiguous molecules)
    const float* centers = (const float*)d_in[3];
    const float* w_rbf   = (const float*)d_in[4];
    const float* b_rbf   = (const float*)d_in[5];
    const float* w_qkv   = (const float*)d_in[6];
    const float* b_qkv   = (const float*)d_in[7];
    const float* w_out   = (const float*)d_in[8];
    const float* b_out   = (const float*)d_in[9];
    const float* gamma   = (const float*)d_in[10];
    const float* beta    = (const float*)d_in[11];
    float* out = (float*)d_out;

    char* ws = (char*)d_ws;
    short* wqT  = (short*)ws;                      // [1536][512] bf16 = 1.5 MB
    short* woT  = (short*)(ws + 1572864);          // [512][512]  bf16 = 0.5 MB
    float* tbl  = (float*)(ws + 2097152);          // [8][1024]   f32  = 32 KB
    short* qkvb = (short*)(ws + 2162688);          // [512][3][8][64][64] bf16 = 100.7 MB

    k_prep_w<<<256, 256, 0, stream>>>(w_qkv, w_out, wqT, woT);
    k_prep_tbl<<<32, 256, 0, stream>>>(centers, w_rbf, b_rbf, tbl);
    for (int half = 0; half < 2; ++half) {
        int molbase = half * 512;
        k_qkv<<<dim3(256, 6), 512, 0, stream>>>(h, b_qkv, wqT, qkvb, molbase);
        k_fused<<<512, 512, 0, stream>>>(qkvb, pos, tbl, h, woT, b_out,
                                         gamma, beta, out, molbase);
    }
}

// Round 6
// 420.625 us; speedup vs baseline: 1.1708x; 1.1708x over previous
//
#include <hip/hip_runtime.h>
#include <hip/hip_bf16.h>

// PointSelfAttention R6:
//   k_prep_w : w_qkv/w_out -> bf16 [col][K]
//   k_prep_tbl : per-head RBF bias table (1024 entries)
//   k_qkv  : GEMM M=128 x N=256/block; A+B LDS double-buffered, ONE barrier per BK=32,
//            global->reg prefetch overlaps MFMA. V panels written transposed [d][key].
//   k_fused: per molecule (8 waves = 8 heads): S=qk^T(+bias), softmax, PV, out-proj,
//            residual+LN. q/k/v/woT frags direct from global; P/agg in swizzled LDS.

#define HID 512
#define TBL 1024
#define DMAX 12.0f

typedef __attribute__((ext_vector_type(4))) float f32x4;
typedef __attribute__((ext_vector_type(8))) short bhalf8;

__device__ __forceinline__ short f2bf(float f) {
    union { float f; unsigned u; } x; x.f = f;
    unsigned u = x.u;
    unsigned r = (u + 0x7FFFu + ((u >> 16) & 1u)) >> 16;  // RNE
    return (short)r;
}

// ---- prep: transpose weights to bf16 [cols][K] ----
__global__ __launch_bounds__(256) void k_prep_w(const float* __restrict__ w_qkv,
                                                const float* __restrict__ w_out,
                                                short* __restrict__ wqT,
                                                short* __restrict__ woT) {
    __shared__ short tile[64][68];
    const int t = threadIdx.x;
    int bt = blockIdx.x;
    const float* src; short* dst; int sld, tk, tc;
    if (bt < 192) { src = w_qkv; dst = wqT; sld = 1536; tk = bt & 7; tc = bt >> 3; }
    else { int b2 = bt - 192; src = w_out; dst = woT; sld = 512; tk = b2 & 7; tc = b2 >> 3; }
#pragma unroll
    for (int p = 0; p < 4; ++p) {
        int s = t + 256 * p;
        int r = s >> 4, sg = s & 15;
        const float4 v = *(const float4*)(src + (tk * 64 + r) * sld + tc * 64 + sg * 4);
        tile[r][sg * 4 + 0] = f2bf(v.x);
        tile[r][sg * 4 + 1] = f2bf(v.y);
        tile[r][sg * 4 + 2] = f2bf(v.z);
        tile[r][sg * 4 + 3] = f2bf(v.w);
    }
    __syncthreads();
#pragma unroll
    for (int p = 0; p < 16; ++p) {
        int o = t + 256 * p;
        int c = o >> 6, k = o & 63;
        dst[(tc * 64 + c) * 512 + tk * 64 + k] = tile[k][c];
    }
}

// ---- prep: per-head bias(d) table [8][1024] ----
__global__ __launch_bounds__(256) void k_prep_tbl(const float* __restrict__ centers,
                                                  const float* __restrict__ w_rbf,
                                                  const float* __restrict__ b_rbf,
                                                  float* __restrict__ tbl) {
    int idx = blockIdx.x * 256 + threadIdx.x;   // 8 heads * 1024
    int hh = idx >> 10, i = idx & (TBL - 1);
    float d = (float)i * (DMAX / (float)(TBL - 1));
    float s = b_rbf[hh];
    const float invw = 1.0f / 0.0625f;          // width = (8/32)^2
#pragma unroll 4
    for (int r = 0; r < 32; ++r) {
        float tt = d - centers[r];
        s += w_rbf[r * 8 + hh] * expf(-(tt * tt) * invw);
    }
    tbl[idx] = s;
}

// ---- QKV GEMM: M=128 x N=256 per block, 8 waves, wave-tile 64x64;
//      A+B LDS double-buffer, 1 barrier per BK=32 ----
__global__ __launch_bounds__(512) void k_qkv(const float* __restrict__ h,
                                             const float* __restrict__ b_qkv,
                                             const short* __restrict__ wqT,
                                             short* __restrict__ qkvb,
                                             int molbase) {
    __shared__ __align__(16) short As[2][128 * 40];    // 20 KB
    __shared__ __align__(16) short Bs[2][256 * 40];    // 40 KB
    const int t = threadIdx.x;
    const int lane = t & 63, wave = t >> 6;
    const int l16 = lane & 15, g = lane >> 4;
    const int wrow = wave >> 2, wcol = wave & 3;       // 2 x 4 wave grid
    const int R0 = molbase * 64 + blockIdx.x * 128;
    const int C0 = blockIdx.y * 256;

    f32x4 acc[4][4];
#pragma unroll
    for (int i = 0; i < 4; ++i)
#pragma unroll
        for (int j = 0; j < 4; ++j) acc[i][j] = (f32x4){0.f, 0.f, 0.f, 0.f};

    const int arow = t >> 2, aseg = t & 3;             // A: 128 rows x 4 int4-slots
    const float* hsrc = h + (size_t)(R0 + arow) * HID + aseg * 8;
    const int bcol = t >> 2, bseg = t & 3;             // B: cols bcol, bcol+128
    const short* bsrc0 = wqT + (size_t)(C0 + bcol) * HID + bseg * 8;
    const short* bsrc1 = wqT + (size_t)(C0 + bcol + 128) * HID + bseg * 8;

    int4 pA, pB0, pB1;
#define QLOADA(kc) {                                                             \
        float4 a0 = *(const float4*)(hsrc + (kc) * 32);                          \
        float4 a1 = *(const float4*)(hsrc + (kc) * 32 + 4);                      \
        short s8[8];                                                             \
        s8[0] = f2bf(a0.x); s8[1] = f2bf(a0.y); s8[2] = f2bf(a0.z); s8[3] = f2bf(a0.w); \
        s8[4] = f2bf(a1.x); s8[5] = f2bf(a1.y); s8[6] = f2bf(a1.z); s8[7] = f2bf(a1.w); \
        pA = *(int4*)s8; }
#define QLOADB(kc) {                                                             \
        pB0 = *(const int4*)(bsrc0 + (kc) * 32);                                 \
        pB1 = *(const int4*)(bsrc1 + (kc) * 32); }
#define QSTAGE(buf) {                                                            \
        *(int4*)(&As[buf][arow * 40 + aseg * 8]) = pA;                           \
        *(int4*)(&Bs[buf][bcol * 40 + bseg * 8]) = pB0;                          \
        *(int4*)(&Bs[buf][(bcol + 128) * 40 + bseg * 8]) = pB1; }

    QLOADA(0); QLOADB(0); QSTAGE(0);
    __syncthreads();

    for (int kc = 0; kc < 16; ++kc) {
        const int cur = kc & 1;
        if (kc < 15) { QLOADA(kc + 1); QLOADB(kc + 1); }
        bhalf8 af[4], bf[4];
#pragma unroll
        for (int mt = 0; mt < 4; ++mt)
            af[mt] = *(const bhalf8*)(&As[cur][(wrow * 64 + mt * 16 + l16) * 40 + g * 8]);
#pragma unroll
        for (int nt = 0; nt < 4; ++nt)
            bf[nt] = *(const bhalf8*)(&Bs[cur][(wcol * 64 + nt * 16 + l16) * 40 + g * 8]);
#pragma unroll
        for (int mt = 0; mt < 4; ++mt)
#pragma unroll
            for (int nt = 0; nt < 4; ++nt)
                acc[mt][nt] = __builtin_amdgcn_mfma_f32_16x16x32_bf16(
                    af[mt], bf[nt], acc[mt][nt], 0, 0, 0);
        if (kc < 15) {
            QSTAGE(cur ^ 1);
            __syncthreads();
        }
    }
#undef QLOADA
#undef QLOADB
#undef QSTAGE

    // epilogue: +bias; q scaled; V written transposed [d][key]
    const int sec = C0 >> 9;
    const float mul = (sec == 0) ? 0.125f : 1.0f;
#pragma unroll
    for (int nt = 0; nt < 4; ++nt) {
        int c = C0 + wcol * 64 + nt * 16 + l16;
        float bv = b_qkv[c];
        int head = (c >> 6) & 7, d = c & 63;
#pragma unroll
        for (int mt = 0; mt < 4; ++mt) {
            int rowg = R0 + wrow * 64 + mt * 16 + g * 4;
            int mol_local = (rowg >> 6) - molbase;
            int rloc = rowg & 63;
            short* panel = qkvb + (size_t)((mol_local * 3 + sec) * 8 + head) * 4096;
            if (sec == 2) {
#pragma unroll
                for (int r = 0; r < 4; ++r)
                    panel[d * 64 + rloc + r] = f2bf(acc[mt][nt][r] + bv);
            } else {
#pragma unroll
                for (int r = 0; r < 4; ++r)
                    panel[(rloc + r) * 64 + d] = f2bf((acc[mt][nt][r] + bv) * mul);
            }
        }
    }
}

// ---- fused attention + out-proj + residual + LayerNorm; 1 block = 1 molecule ----
__global__ __launch_bounds__(512) void k_fused(const short* __restrict__ qkvb,
                                               const float* __restrict__ pos,
                                               const float* __restrict__ tbl,
                                               const float* __restrict__ h,
                                               const short* __restrict__ woT,
                                               const float* __restrict__ b_out,
                                               const float* __restrict__ gamma,
                                               const float* __restrict__ beta,
                                               float* __restrict__ out,
                                               int molbase) {
    __shared__ __align__(16) short uP[8 * 4096];   // per-wave P[64][64] -> agg[64][512]
    __shared__ float s_tbl[8 * 1032];
    __shared__ float s_px[64], s_py[64], s_pz[64];
    __shared__ float red[64 * 16];
    __shared__ float mr[64 * 2];

    const int t = threadIdx.x;
    const int wave = t >> 6, lane = t & 63;
    const int l16 = lane & 15, g = lane >> 4;
    const int mol_local = blockIdx.x;
    const int rowbase = (molbase + mol_local) * 64;

    for (int i = t; i < 8 * TBL; i += 512)
        s_tbl[(i >> 10) * 1032 + (i & (TBL - 1))] = tbl[i];
    if (t < 64) {
        s_px[t] = pos[(rowbase + t) * 3 + 0];
        s_py[t] = pos[(rowbase + t) * 3 + 1];
        s_pz[t] = pos[(rowbase + t) * 3 + 2];
    }
    __syncthreads();

    const short* qp = qkvb + ((size_t)(mol_local * 3 + 0) * 8 + wave) * 4096;
    const short* kp = qkvb + ((size_t)(mol_local * 3 + 1) * 8 + wave) * 4096;
    const short* vt = qkvb + ((size_t)(mol_local * 3 + 2) * 8 + wave) * 4096;  // [d][key]

    // ---- S = q_scaled . k^T (wave owns full 64x64 of its head) ----
    f32x4 sacc[4][4];
#pragma unroll
    for (int i = 0; i < 4; ++i)
#pragma unroll
        for (int j = 0; j < 4; ++j) sacc[i][j] = (f32x4){0.f, 0.f, 0.f, 0.f};
#pragma unroll
    for (int kk = 0; kk < 2; ++kk) {
        bhalf8 qa[4], kb[4];
#pragma unroll
        for (int mt = 0; mt < 4; ++mt)
            qa[mt] = *(const bhalf8*)(qp + (mt * 16 + l16) * 64 + kk * 32 + g * 8);
#pragma unroll
        for (int nt = 0; nt < 4; ++nt)
            kb[nt] = *(const bhalf8*)(kp + (nt * 16 + l16) * 64 + kk * 32 + g * 8);
#pragma unroll
        for (int mt = 0; mt < 4; ++mt)
#pragma unroll
            for (int nt = 0; nt < 4; ++nt)
                sacc[mt][nt] = __builtin_amdgcn_mfma_f32_16x16x32_bf16(
                    qa[mt], kb[nt], sacc[mt][nt], 0, 0, 0);
    }

    // ---- + RBF bias (LDS table) ----
    const float tscale = (float)(TBL - 1) / DMAX;
    const float* T = s_tbl + wave * 1032;
#pragma unroll
    for (int nt = 0; nt < 4; ++nt) {
        int col = nt * 16 + l16;
        float cx = s_px[col], cy = s_py[col], cz = s_pz[col];
#pragma unroll
        for (int mt = 0; mt < 4; ++mt) {
#pragma unroll
            for (int r = 0; r < 4; ++r) {
                int row = mt * 16 + g * 4 + r;
                float dx = s_px[row] - cx, dy = s_py[row] - cy, dz = s_pz[row] - cz;
                float dd = fmaf(dx, dx, fmaf(dy, dy, dz * dz));
                float dist = sqrtf(fmaxf(dd, 1e-12f));
                float u = fminf(dist, DMAX) * tscale;
                int i = (int)u; if (i > TBL - 2) i = TBL - 2;
                float fr = u - (float)i;
                float t0 = T[i];
                sacc[mt][nt][r] += fmaf(fr, T[i + 1] - t0, t0);
            }
        }
    }

    // ---- softmax rows + P (XOR-swizzled 16-B groups) ----
    float inv[4][4];
    short* Pw = uP + wave * 4096;
#pragma unroll
    for (int mt = 0; mt < 4; ++mt) {
#pragma unroll
        for (int r = 0; r < 4; ++r) {
            float m = fmaxf(fmaxf(sacc[mt][0][r], sacc[mt][1][r]),
                            fmaxf(sacc[mt][2][r], sacc[mt][3][r]));
#pragma unroll
            for (int off = 1; off < 16; off <<= 1) m = fmaxf(m, __shfl_xor(m, off, 64));
            float e[4], ssum = 0.f;
#pragma unroll
            for (int nt = 0; nt < 4; ++nt) { e[nt] = __expf(sacc[mt][nt][r] - m); ssum += e[nt]; }
#pragma unroll
            for (int off = 1; off < 16; off <<= 1) ssum += __shfl_xor(ssum, off, 64);
            inv[mt][r] = 1.0f / ssum;
            int row = mt * 16 + g * 4 + r;
            int rho = row & 7;
#pragma unroll
            for (int nt = 0; nt < 4; ++nt) {
                int c = nt * 16 + l16;
                Pw[row * 64 + (((c >> 3) ^ rho) << 3) + (c & 7)] = f2bf(e[nt]);
            }
        }
    }

    // ---- PV: agg_head = P @ V  (V^T frags direct from global) ----
    f32x4 oacc[4][4];
#pragma unroll
    for (int i = 0; i < 4; ++i)
#pragma unroll
        for (int j = 0; j < 4; ++j) oacc[i][j] = (f32x4){0.f, 0.f, 0.f, 0.f};
#pragma unroll
    for (int kk = 0; kk < 2; ++kk) {
        bhalf8 pa[4], vb[4];
#pragma unroll
        for (int mt = 0; mt < 4; ++mt)
            pa[mt] = *(const bhalf8*)(Pw + (mt * 16 + l16) * 64 +
                                      (((kk * 4 + g) ^ (l16 & 7)) << 3));
#pragma unroll
        for (int nt = 0; nt < 4; ++nt)
            vb[nt] = *(const bhalf8*)(vt + (nt * 16 + l16) * 64 + kk * 32 + g * 8);
#pragma unroll
        for (int mt = 0; mt < 4; ++mt)
#pragma unroll
            for (int nt = 0; nt < 4; ++nt)
                oacc[mt][nt] = __builtin_amdgcn_mfma_f32_16x16x32_bf16(
                    pa[mt], vb[nt], oacc[mt][nt], 0, 0, 0);
    }
#pragma unroll
    for (int mt = 0; mt < 4; ++mt)
#pragma unroll
        for (int nt = 0; nt < 4; ++nt)
#pragma unroll
            for (int r = 0; r < 4; ++r) oacc[mt][nt][r] *= inv[mt][r];

    __syncthreads();   // all waves done reading P; uP becomes agg[64][512]

#pragma unroll
    for (int mt = 0; mt < 4; ++mt) {
#pragma unroll
        for (int r = 0; r < 4; ++r) {
            int row = mt * 16 + g * 4 + r;
            int rho = row & 7;
#pragma unroll
            for (int nt = 0; nt < 4; ++nt) {
                int c = wave * 64 + nt * 16 + l16;
                uP[row * 512 + (((c >> 3) ^ rho) << 3) + (c & 7)] = f2bf(oacc[mt][nt][r]);
            }
        }
    }
    __syncthreads();

    // ---- out-proj: wave owns cols wave*64..+63; woT frags from L2; no barriers ----
    f32x4 pacc[4][4];
#pragma unroll
    for (int i = 0; i < 4; ++i)
#pragma unroll
        for (int j = 0; j < 4; ++j) pacc[i][j] = (f32x4){0.f, 0.f, 0.f, 0.f};
#pragma unroll 4
    for (int kc = 0; kc < 16; ++kc) {
        bhalf8 af[4], bw[4];
#pragma unroll
        for (int mt = 0; mt < 4; ++mt)
            af[mt] = *(const bhalf8*)(uP + (mt * 16 + l16) * 512 +
                                      (((kc * 4 + g) ^ (l16 & 7)) << 3));
#pragma unroll
        for (int nt = 0; nt < 4; ++nt)
            bw[nt] = *(const bhalf8*)(woT + (size_t)(wave * 64 + nt * 16 + l16) * HID +
                                      kc * 32 + g * 8);
#pragma unroll
        for (int mt = 0; mt < 4; ++mt)
#pragma unroll
            for (int nt = 0; nt < 4; ++nt)
                pacc[mt][nt] = __builtin_amdgcn_mfma_f32_16x16x32_bf16(
                    af[mt], bw[nt], pacc[mt][nt], 0, 0, 0);
    }

    // ---- + b_out + residual; LN partials ----
#pragma unroll
    for (int mt = 0; mt < 4; ++mt) {
#pragma unroll
        for (int r = 0; r < 4; ++r) {
            int row = mt * 16 + g * 4 + r;
            float rs = 0.f, rq = 0.f;
#pragma unroll
            for (int nt = 0; nt < 4; ++nt) {
                int col = wave * 64 + nt * 16 + l16;
                float v = pacc[mt][nt][r] + b_out[col] +
                          h[(size_t)(rowbase + row) * HID + col];
                pacc[mt][nt][r] = v;
                rs += v;
                rq = fmaf(v, v, rq);
            }
#pragma unroll
            for (int off = 1; off < 16; off <<= 1) {
                rs += __shfl_xor(rs, off, 64);
                rq += __shfl_xor(rq, off, 64);
            }
            if (l16 == 0) {
                red[row * 16 + wave * 2 + 0] = rs;
                red[row * 16 + wave * 2 + 1] = rq;
            }
        }
    }
    __syncthreads();
    if (t < 64) {
        float s = 0.f, q = 0.f;
#pragma unroll
        for (int w = 0; w < 8; ++w) {
            s += red[t * 16 + w * 2 + 0];
            q += red[t * 16 + w * 2 + 1];
        }
        float mean = s * (1.0f / 512.0f);
        float var = q * (1.0f / 512.0f) - mean * mean;
        mr[t * 2 + 0] = mean;
        mr[t * 2 + 1] = rsqrtf(var + 1e-5f);
    }
    __syncthreads();
#pragma unroll
    for (int mt = 0; mt < 4; ++mt) {
#pragma unroll
        for (int r = 0; r < 4; ++r) {
            int row = mt * 16 + g * 4 + r;
            float mean = mr[row * 2 + 0], rstd = mr[row * 2 + 1];
#pragma unroll
            for (int nt = 0; nt < 4; ++nt) {
                int col = wave * 64 + nt * 16 + l16;
                out[(size_t)(rowbase + row) * HID + col] =
                    fmaf((pacc[mt][nt][r] - mean) * rstd, gamma[col], beta[col]);
            }
        }
    }
}

extern "C" void kernel_launch(void* const* d_in, const int* in_sizes, int n_in,
                              void* d_out, int out_size, void* d_ws, size_t ws_size,
                              hipStream_t stream) {
    (void)in_sizes; (void)n_in; (void)out_size; (void)ws_size;
    const float* h       = (const float*)d_in[0];
    const float* pos     = (const float*)d_in[1];
    // d_in[2] = batch (unused: equal-size contiguous molecules)
    const float* centers = (const float*)d_in[3];
    const float* w_rbf   = (const float*)d_in[4];
    const float* b_rbf   = (const float*)d_in[5];
    const float* w_qkv   = (const float*)d_in[6];
    const float* b_qkv   = (const float*)d_in[7];
    const float* w_out   = (const float*)d_in[8];
    const float* b_out   = (const float*)d_in[9];
    const float* gamma   = (const float*)d_in[10];
    const float* beta    = (const float*)d_in[11];
    float* out = (float*)d_out;

    char* ws = (char*)d_ws;
    short* wqT  = (short*)ws;                      // [1536][512] bf16 = 1.5 MB
    short* woT  = (short*)(ws + 1572864);          // [512][512]  bf16 = 0.5 MB
    float* tbl  = (float*)(ws + 2097152);          // [8][1024]   f32  = 32 KB
    short* qkvb = (short*)(ws + 2162688);          // [512][3][8][64][64] bf16 = 100.7 MB

    k_prep_w<<<256, 256, 0, stream>>>(w_qkv, w_out, wqT, woT);
    k_prep_tbl<<<32, 256, 0, stream>>>(centers, w_rbf, b_rbf, tbl);
    for (int half = 0; half < 2; ++half) {
        int molbase = half * 512;
        k_qkv<<<dim3(256, 6), 512, 0, stream>>>(h, b_qkv, wqT, qkvb, molbase);
        k_fused<<<512, 512, 0, stream>>>(qkvb, pos, tbl, h, woT, b_out,
                                         gamma, beta, out, molbase);
    }
}

// Round 7
// 408.709 us; speedup vs baseline: 1.2050x; 1.0292x over previous
//
#include <hip/hip_runtime.h>
#include <hip/hip_bf16.h>

// PointSelfAttention R7:
//   k_prep_w  : w_qkv -> bf16 [col][K] PRE-SWIZZLED (c^=(row&7)<<3 per 64-short chunk);
//               w_out -> bf16 [col][K] plain (consumed as direct frags in k_fused)
//   k_prep_tbl: per-head RBF bias table (1024 entries)
//   k_prep_h  : h fp32 -> bf16, pre-swizzled, per half (for global_load_lds staging)
//   k_qkv     : m97-style GEMM 128x256 tile BK=64, global_load_lds both operands,
//               48KB single-buffer LDS (3 blocks/CU), swizzled ds_reads. V stored [d][key].
//   k_fused   : per molecule (8 waves = 8 heads): QK^T+bias, softmax, PV, out-proj,
//               residual+LN (unchanged from R6).

#define HID 512
#define TBL 1024
#define DMAX 12.0f

typedef __attribute__((ext_vector_type(4))) float f32x4;
typedef __attribute__((ext_vector_type(8))) short bhalf8;

__device__ __forceinline__ short f2bf(float f) {
    union { float f; unsigned u; } x; x.f = f;
    unsigned u = x.u;
    unsigned r = (u + 0x7FFFu + ((u >> 16) & 1u)) >> 16;  // RNE
    return (short)r;
}

__device__ __forceinline__ void gld_lds16(const void* g, void* l) {
    __builtin_amdgcn_global_load_lds((const __attribute__((address_space(1))) void*)g,
                                     (__attribute__((address_space(3))) void*)l, 16, 0, 0);
}

// ---- prep: transpose weights to bf16 [cols][K]; wqT pre-swizzled ----
__global__ __launch_bounds__(256) void k_prep_w(const float* __restrict__ w_qkv,
                                                const float* __restrict__ w_out,
                                                short* __restrict__ wqT,
                                                short* __restrict__ woT) {
    __shared__ short tile[64][68];
    const int t = threadIdx.x;
    int bt = blockIdx.x;
    const float* src; short* dst; int sld, tk, tc, swz;
    if (bt < 192) { src = w_qkv; dst = wqT; sld = 1536; tk = bt & 7; tc = bt >> 3; swz = 1; }
    else { int b2 = bt - 192; src = w_out; dst = woT; sld = 512; tk = b2 & 7; tc = b2 >> 3; swz = 0; }
#pragma unroll
    for (int p = 0; p < 4; ++p) {
        int s = t + 256 * p;
        int r = s >> 4, sg = s & 15;
        const float4 v = *(const float4*)(src + (tk * 64 + r) * sld + tc * 64 + sg * 4);
        tile[r][sg * 4 + 0] = f2bf(v.x);
        tile[r][sg * 4 + 1] = f2bf(v.y);
        tile[r][sg * 4 + 2] = f2bf(v.z);
        tile[r][sg * 4 + 3] = f2bf(v.w);
    }
    __syncthreads();
#pragma unroll
    for (int p = 0; p < 16; ++p) {
        int o = t + 256 * p;
        int c = o >> 6, k = o & 63;
        int kk = swz ? (k ^ ((c & 7) << 3)) : k;
        dst[(tc * 64 + c) * 512 + tk * 64 + kk] = tile[k][c];
    }
}

// ---- prep: per-head bias(d) table [8][1024] ----
__global__ __launch_bounds__(256) void k_prep_tbl(const float* __restrict__ centers,
                                                  const float* __restrict__ w_rbf,
                                                  const float* __restrict__ b_rbf,
                                                  float* __restrict__ tbl) {
    int idx = blockIdx.x * 256 + threadIdx.x;   // 8 heads * 1024
    int hh = idx >> 10, i = idx & (TBL - 1);
    float d = (float)i * (DMAX / (float)(TBL - 1));
    float s = b_rbf[hh];
    const float invw = 1.0f / 0.0625f;          // width = (8/32)^2
#pragma unroll 4
    for (int r = 0; r < 32; ++r) {
        float tt = d - centers[r];
        s += w_rbf[r * 8 + hh] * expf(-(tt * tt) * invw);
    }
    tbl[idx] = s;
}

// ---- prep: h (fp32) -> bf16 pre-swizzled, one half (32768 rows) ----
__global__ __launch_bounds__(256) void k_prep_h(const float* __restrict__ h,
                                                short* __restrict__ hbf,
                                                int molbase) {
    size_t i = ((size_t)blockIdx.x * 256 + threadIdx.x) * 8;   // short idx within half
    const float* src = h + (size_t)molbase * 64 * HID + i;
    float4 a = *(const float4*)src;
    float4 b = *(const float4*)(src + 4);
    short s8[8];
    s8[0] = f2bf(a.x); s8[1] = f2bf(a.y); s8[2] = f2bf(a.z); s8[3] = f2bf(a.w);
    s8[4] = f2bf(b.x); s8[5] = f2bf(b.y); s8[6] = f2bf(b.z); s8[7] = f2bf(b.w);
    int row = (int)(i >> 9);
    size_t o = i ^ (size_t)((row & 7) << 3);   // swizzle 16B slots within 64-short chunk
    *(int4*)(hbf + o) = *(int4*)s8;
}

// ---- QKV GEMM (m97-style): 128x256 tile, BK=64, global_load_lds, 1 buffer ----
__global__ __launch_bounds__(512) void k_qkv(const short* __restrict__ hbf,
                                             const float* __restrict__ b_qkv,
                                             const short* __restrict__ wqT,
                                             short* __restrict__ qkvb) {
    __shared__ __align__(16) short As[128 * 64];   // 16 KB
    __shared__ __align__(16) short Bs[256 * 64];   // 32 KB
    const int t = threadIdx.x;
    const int lane = t & 63, wave = t >> 6;
    const int l16 = lane & 15, g = lane >> 4;
    const int wrow = wave >> 2, wcol = wave & 3;   // 2 x 4 wave grid

    int wg = blockIdx.x;                           // 1536 wgs; %8==0 -> simple XCD swizzle
    wg = (wg & 7) * 192 + (wg >> 3);
    const int bx = wg & 255, by = wg >> 8;         // 256 x-blocks, 6 y-blocks
    const int R0l = bx * 128;                      // local row base within half
    const int C0 = by * 256;

    f32x4 acc[4][4];
#pragma unroll
    for (int i = 0; i < 4; ++i)
#pragma unroll
        for (int j = 0; j < 4; ++j) acc[i][j] = (f32x4){0.f, 0.f, 0.f, 0.f};

    const int lrow = lane >> 3, lslot = lane & 7;  // per-lane gload mapping
    const int axor = (l16 & 7) << 3;               // read-side swizzle (row&7 == l16&7)

    for (int kc = 0; kc < 8; ++kc) {
        const int kb = kc * 64;
        // stage A: 128x64 bf16 = 16KB = 2 ops/wave of 1KB
#pragma unroll
        for (int j = 0; j < 2; ++j) {
            int row = wave * 16 + j * 8 + lrow;
            gld_lds16(hbf + (size_t)(R0l + row) * HID + kb + lslot * 8,
                      (char*)As + wave * 2048 + j * 1024 + lane * 16);
        }
        // stage B: 256x64 bf16 = 32KB = 4 ops/wave
#pragma unroll
        for (int j = 0; j < 4; ++j) {
            int row = wave * 32 + j * 8 + lrow;
            gld_lds16(wqT + (size_t)(C0 + row) * HID + kb + lslot * 8,
                      (char*)Bs + wave * 4096 + j * 1024 + lane * 16);
        }
        __syncthreads();                            // vmcnt(0) drain + barrier
#pragma unroll
        for (int kk = 0; kk < 2; ++kk) {
            const int c8 = kk * 32 + g * 8;
            const int cs = c8 ^ axor;
            bhalf8 af[4], bf[4];
#pragma unroll
            for (int mt = 0; mt < 4; ++mt)
                af[mt] = *(const bhalf8*)(&As[(wrow * 64 + mt * 16 + l16) * 64 + cs]);
#pragma unroll
            for (int nt = 0; nt < 4; ++nt)
                bf[nt] = *(const bhalf8*)(&Bs[(wcol * 64 + nt * 16 + l16) * 64 + cs]);
#pragma unroll
            for (int mt = 0; mt < 4; ++mt)
#pragma unroll
                for (int nt = 0; nt < 4; ++nt)
                    acc[mt][nt] = __builtin_amdgcn_mfma_f32_16x16x32_bf16(
                        af[mt], bf[nt], acc[mt][nt], 0, 0, 0);
        }
        __syncthreads();                            // protect buffer before next stage
    }

    // epilogue: +bias; q scaled; V written transposed [d][key] (short4-combined)
    const int sec = C0 >> 9;
    const float mul = (sec == 0) ? 0.125f : 1.0f;
#pragma unroll
    for (int nt = 0; nt < 4; ++nt) {
        int c = C0 + wcol * 64 + nt * 16 + l16;
        float bv = b_qkv[c];
        int head = (c >> 6) & 7, d = c & 63;
#pragma unroll
        for (int mt = 0; mt < 4; ++mt) {
            int rowl = R0l + wrow * 64 + mt * 16 + g * 4;
            int mol_local = rowl >> 6;
            int rloc = rowl & 63;
            short* panel = qkvb + (size_t)((mol_local * 3 + sec) * 8 + head) * 4096;
            if (sec == 2) {
                short4 s4;
                s4.x = f2bf(acc[mt][nt][0] + bv);
                s4.y = f2bf(acc[mt][nt][1] + bv);
                s4.z = f2bf(acc[mt][nt][2] + bv);
                s4.w = f2bf(acc[mt][nt][3] + bv);
                *(short4*)(panel + d * 64 + rloc) = s4;
            } else {
#pragma unroll
                for (int r = 0; r < 4; ++r)
                    panel[(rloc + r) * 64 + d] = f2bf((acc[mt][nt][r] + bv) * mul);
            }
        }
    }
}

// ---- fused attention + out-proj + residual + LayerNorm; 1 block = 1 molecule ----
__global__ __launch_bounds__(512) void k_fused(const short* __restrict__ qkvb,
                                               const float* __restrict__ pos,
                                               const float* __restrict__ tbl,
                                               const float* __restrict__ h,
                                               const short* __restrict__ woT,
                                               const float* __restrict__ b_out,
                                               const float* __restrict__ gamma,
                                               const float* __restrict__ beta,
                                               float* __restrict__ out,
                                               int molbase) {
    __shared__ __align__(16) short uP[8 * 4096];   // per-wave P[64][64] -> agg[64][512]
    __shared__ float s_tbl[8 * 1032];
    __shared__ float s_px[64], s_py[64], s_pz[64];
    __shared__ float red[64 * 16];
    __shared__ float mr[64 * 2];

    const int t = threadIdx.x;
    const int wave = t >> 6, lane = t & 63;
    const int l16 = lane & 15, g = lane >> 4;
    const int mol_local = blockIdx.x;
    const int rowbase = (molbase + mol_local) * 64;

    for (int i = t; i < 8 * TBL; i += 512)
        s_tbl[(i >> 10) * 1032 + (i & (TBL - 1))] = tbl[i];
    if (t < 64) {
        s_px[t] = pos[(rowbase + t) * 3 + 0];
        s_py[t] = pos[(rowbase + t) * 3 + 1];
        s_pz[t] = pos[(rowbase + t) * 3 + 2];
    }
    __syncthreads();

    const short* qp = qkvb + ((size_t)(mol_local * 3 + 0) * 8 + wave) * 4096;
    const short* kp = qkvb + ((size_t)(mol_local * 3 + 1) * 8 + wave) * 4096;
    const short* vt = qkvb + ((size_t)(mol_local * 3 + 2) * 8 + wave) * 4096;  // [d][key]

    // ---- S = q_scaled . k^T (wave owns full 64x64 of its head) ----
    f32x4 sacc[4][4];
#pragma unroll
    for (int i = 0; i < 4; ++i)
#pragma unroll
        for (int j = 0; j < 4; ++j) sacc[i][j] = (f32x4){0.f, 0.f, 0.f, 0.f};
#pragma unroll
    for (int kk = 0; kk < 2; ++kk) {
        bhalf8 qa[4], kb[4];
#pragma unroll
        for (int mt = 0; mt < 4; ++mt)
            qa[mt] = *(const bhalf8*)(qp + (mt * 16 + l16) * 64 + kk * 32 + g * 8);
#pragma unroll
        for (int nt = 0; nt < 4; ++nt)
            kb[nt] = *(const bhalf8*)(kp + (nt * 16 + l16) * 64 + kk * 32 + g * 8);
#pragma unroll
        for (int mt = 0; mt < 4; ++mt)
#pragma unroll
            for (int nt = 0; nt < 4; ++nt)
                sacc[mt][nt] = __builtin_amdgcn_mfma_f32_16x16x32_bf16(
                    qa[mt], kb[nt], sacc[mt][nt], 0, 0, 0);
    }

    // ---- + RBF bias (LDS table) ----
    const float tscale = (float)(TBL - 1) / DMAX;
    const float* T = s_tbl + wave * 1032;
#pragma unroll
    for (int nt = 0; nt < 4; ++nt) {
        int col = nt * 16 + l16;
        float cx = s_px[col], cy = s_py[col], cz = s_pz[col];
#pragma unroll
        for (int mt = 0; mt < 4; ++mt) {
#pragma unroll
            for (int r = 0; r < 4; ++r) {
                int row = mt * 16 + g * 4 + r;
                float dx = s_px[row] - cx, dy = s_py[row] - cy, dz = s_pz[row] - cz;
                float dd = fmaf(dx, dx, fmaf(dy, dy, dz * dz));
                float dist = sqrtf(fmaxf(dd, 1e-12f));
                float u = fminf(dist, DMAX) * tscale;
                int i = (int)u; if (i > TBL - 2) i = TBL - 2;
                float fr = u - (float)i;
                float t0 = T[i];
                sacc[mt][nt][r] += fmaf(fr, T[i + 1] - t0, t0);
            }
        }
    }

    // ---- softmax rows + P (XOR-swizzled 16-B groups) ----
    float inv[4][4];
    short* Pw = uP + wave * 4096;
#pragma unroll
    for (int mt = 0; mt < 4; ++mt) {
#pragma unroll
        for (int r = 0; r < 4; ++r) {
            float m = fmaxf(fmaxf(sacc[mt][0][r], sacc[mt][1][r]),
                            fmaxf(sacc[mt][2][r], sacc[mt][3][r]));
#pragma unroll
            for (int off = 1; off < 16; off <<= 1) m = fmaxf(m, __shfl_xor(m, off, 64));
            float e[4], ssum = 0.f;
#pragma unroll
            for (int nt = 0; nt < 4; ++nt) { e[nt] = __expf(sacc[mt][nt][r] - m); ssum += e[nt]; }
#pragma unroll
            for (int off = 1; off < 16; off <<= 1) ssum += __shfl_xor(ssum, off, 64);
            inv[mt][r] = 1.0f / ssum;
            int row = mt * 16 + g * 4 + r;
            int rho = row & 7;
#pragma unroll
            for (int nt = 0; nt < 4; ++nt) {
                int c = nt * 16 + l16;
                Pw[row * 64 + (((c >> 3) ^ rho) << 3) + (c & 7)] = f2bf(e[nt]);
            }
        }
    }

    // ---- PV: agg_head = P @ V  (V^T frags direct from global) ----
    f32x4 oacc[4][4];
#pragma unroll
    for (int i = 0; i < 4; ++i)
#pragma unroll
        for (int j = 0; j < 4; ++j) oacc[i][j] = (f32x4){0.f, 0.f, 0.f, 0.f};
#pragma unroll
    for (int kk = 0; kk < 2; ++kk) {
        bhalf8 pa[4], vb[4];
#pragma unroll
        for (int mt = 0; mt < 4; ++mt)
            pa[mt] = *(const bhalf8*)(Pw + (mt * 16 + l16) * 64 +
                                      (((kk * 4 + g) ^ (l16 & 7)) << 3));
#pragma unroll
        for (int nt = 0; nt < 4; ++nt)
            vb[nt] = *(const bhalf8*)(vt + (nt * 16 + l16) * 64 + kk * 32 + g * 8);
#pragma unroll
        for (int mt = 0; mt < 4; ++mt)
#pragma unroll
            for (int nt = 0; nt < 4; ++nt)
                oacc[mt][nt] = __builtin_amdgcn_mfma_f32_16x16x32_bf16(
                    pa[mt], vb[nt], oacc[mt][nt], 0, 0, 0);
    }
#pragma unroll
    for (int mt = 0; mt < 4; ++mt)
#pragma unroll
        for (int nt = 0; nt < 4; ++nt)
#pragma unroll
            for (int r = 0; r < 4; ++r) oacc[mt][nt][r] *= inv[mt][r];

    __syncthreads();   // all waves done reading P; uP becomes agg[64][512]

#pragma unroll
    for (int mt = 0; mt < 4; ++mt) {
#pragma unroll
        for (int r = 0; r < 4; ++r) {
            int row = mt * 16 + g * 4 + r;
            int rho = row & 7;
#pragma unroll
            for (int nt = 0; nt < 4; ++nt) {
                int c = wave * 64 + nt * 16 + l16;
                uP[row * 512 + (((c >> 3) ^ rho) << 3) + (c & 7)] = f2bf(oacc[mt][nt][r]);
            }
        }
    }
    __syncthreads();

    // ---- out-proj: wave owns cols wave*64..+63; woT frags from L2; no barriers ----
    f32x4 pacc[4][4];
#pragma unroll
    for (int i = 0; i < 4; ++i)
#pragma unroll
        for (int j = 0; j < 4; ++j) pacc[i][j] = (f32x4){0.f, 0.f, 0.f, 0.f};
#pragma unroll 4
    for (int kc = 0; kc < 16; ++kc) {
        bhalf8 af[4], bw[4];
#pragma unroll
        for (int mt = 0; mt < 4; ++mt)
            af[mt] = *(const bhalf8*)(uP + (mt * 16 + l16) * 512 +
                                      (((kc * 4 + g) ^ (l16 & 7)) << 3));
#pragma unroll
        for (int nt = 0; nt < 4; ++nt)
            bw[nt] = *(const bhalf8*)(woT + (size_t)(wave * 64 + nt * 16 + l16) * HID +
                                      kc * 32 + g * 8);
#pragma unroll
        for (int mt = 0; mt < 4; ++mt)
#pragma unroll
            for (int nt = 0; nt < 4; ++nt)
                pacc[mt][nt] = __builtin_amdgcn_mfma_f32_16x16x32_bf16(
                    af[mt], bw[nt], pacc[mt][nt], 0, 0, 0);
    }

    // ---- + b_out + residual; LN partials ----
#pragma unroll
    for (int mt = 0; mt < 4; ++mt) {
#pragma unroll
        for (int r = 0; r < 4; ++r) {
            int row = mt * 16 + g * 4 + r;
            float rs = 0.f, rq = 0.f;
#pragma unroll
            for (int nt = 0; nt < 4; ++nt) {
                int col = wave * 64 + nt * 16 + l16;
                float v = pacc[mt][nt][r] + b_out[col] +
                          h[(size_t)(rowbase + row) * HID + col];
                pacc[mt][nt][r] = v;
                rs += v;
                rq = fmaf(v, v, rq);
            }
#pragma unroll
            for (int off = 1; off < 16; off <<= 1) {
                rs += __shfl_xor(rs, off, 64);
                rq += __shfl_xor(rq, off, 64);
            }
            if (l16 == 0) {
                red[row * 16 + wave * 2 + 0] = rs;
                red[row * 16 + wave * 2 + 1] = rq;
            }
        }
    }
    __syncthreads();
    if (t < 64) {
        float s = 0.f, q = 0.f;
#pragma unroll
        for (int w = 0; w < 8; ++w) {
            s += red[t * 16 + w * 2 + 0];
            q += red[t * 16 + w * 2 + 1];
        }
        float mean = s * (1.0f / 512.0f);
        float var = q * (1.0f / 512.0f) - mean * mean;
        mr[t * 2 + 0] = mean;
        mr[t * 2 + 1] = rsqrtf(var + 1e-5f);
    }
    __syncthreads();
#pragma unroll
    for (int mt = 0; mt < 4; ++mt) {
#pragma unroll
        for (int r = 0; r < 4; ++r) {
            int row = mt * 16 + g * 4 + r;
            float mean = mr[row * 2 + 0], rstd = mr[row * 2 + 1];
#pragma unroll
            for (int nt = 0; nt < 4; ++nt) {
                int col = wave * 64 + nt * 16 + l16;
                out[(size_t)(rowbase + row) * HID + col] =
                    fmaf((pacc[mt][nt][r] - mean) * rstd, gamma[col], beta[col]);
            }
        }
    }
}

extern "C" void kernel_launch(void* const* d_in, const int* in_sizes, int n_in,
                              void* d_out, int out_size, void* d_ws, size_t ws_size,
                              hipStream_t stream) {
    (void)in_sizes; (void)n_in; (void)out_size; (void)ws_size;
    const float* h       = (const float*)d_in[0];
    const float* pos     = (const float*)d_in[1];
    // d_in[2] = batch (unused: equal-size contiguous molecules)
    const float* centers = (const float*)d_in[3];
    const float* w_rbf   = (const float*)d_in[4];
    const float* b_rbf   = (const float*)d_in[5];
    const float* w_qkv   = (const float*)d_in[6];
    const float* b_qkv   = (const float*)d_in[7];
    const float* w_out   = (const float*)d_in[8];
    const float* b_out   = (const float*)d_in[9];
    const float* gamma   = (const float*)d_in[10];
    const float* beta    = (const float*)d_in[11];
    float* out = (float*)d_out;

    char* ws = (char*)d_ws;
    short* wqT  = (short*)ws;                      // [1536][512] bf16 = 1.5 MB (swizzled)
    short* woT  = (short*)(ws + 1572864);          // [512][512]  bf16 = 0.5 MB (plain)
    float* tbl  = (float*)(ws + 2097152);          // [8][1024]   f32  = 32 KB
    short* hbf  = (short*)(ws + 2162688);          // [32768][512] bf16 = 32 MB (half, swizzled)
    short* qkvb = (short*)(ws + 35717120);         // [512][3][8][64][64] bf16 = 50.3 MB (half)

    k_prep_w<<<256, 256, 0, stream>>>(w_qkv, w_out, wqT, woT);
    k_prep_tbl<<<32, 256, 0, stream>>>(centers, w_rbf, b_rbf, tbl);
    for (int half = 0; half < 2; ++half) {
        int molbase = half * 512;
        k_prep_h<<<8192, 256, 0, stream>>>(h, hbf, molbase);
        k_qkv<<<1536, 512, 0, stream>>>(hbf, b_qkv, wqT, qkvb);
        k_fused<<<512, 512, 0, stream>>>(qkvb, pos, tbl, h, woT, b_out,
                                         gamma, beta, out, molbase);
    }
}